// Round 5
// baseline (1084.173 us; speedup 1.0000x reference)
//
#include <hip/hip_runtime.h>
#include <hip/hip_bf16.h>
#include <math.h>
#include <stdint.h>

#define N_ROWS 8192
#define M_FACTS 8192
#define D_DIM 1024

typedef __bf16 bf16x8_t __attribute__((ext_vector_type(8)));
typedef __bf16 bf16x4_t __attribute__((ext_vector_type(4)));
typedef float f32x4_t __attribute__((ext_vector_type(4)));

#define BM 128
#define BN 128
#define BK 32
#define PADK 40  // legacy padded stride for fallback kernels

// Async global->LDS, 16B per lane. LDS dest = wave-uniform base + lane*16.
__device__ __forceinline__ void gload_lds16(const void* g, void* lds) {
  __builtin_amdgcn_global_load_lds(
      (__attribute__((address_space(1))) void*)(uintptr_t)g,
      (__attribute__((address_space(3))) void*)(uint32_t)(uintptr_t)lds,
      16, 0, 0);
}

// =========================================================================
// Precompute kernels
// =========================================================================

__global__ __launch_bounds__(256) void split_hi_lo(const float* __restrict__ X,
                                                   __bf16* __restrict__ H,
                                                   __bf16* __restrict__ L) {
  int i = blockIdx.x * 256 + threadIdx.x;
  float4 v = ((const float4*)X)[i];
  float f[4] = {v.x, v.y, v.z, v.w};
  bf16x4_t h, l;
#pragma unroll
  for (int q = 0; q < 4; q++) {
    __bf16 hh = (__bf16)f[q];
    h[q] = hh;
    l[q] = (__bf16)(f[q] - (float)hh);
  }
  ((bf16x4_t*)H)[i] = h;
  ((bf16x4_t*)L)[i] = l;
}

// F fp32 [M][D] -> Ft bf16 [D][M]. 64x64 tiles; fp32 LDS tile stride 69
// (<=2-way banks both phases); global writes coalesced 128B per 8 lanes.
__global__ __launch_bounds__(256) void transpose_f_bf16(const float* __restrict__ F,
                                                        __bf16* __restrict__ Ft) {
  __shared__ float t[64 * 69];
  const int tid = threadIdx.x;
  const int m0 = blockIdx.x * 64, d0 = blockIdx.y * 64;
#pragma unroll
  for (int p = 0; p < 4; p++) {
    int flat = p * 256 + tid;
    int m = flat >> 4, dq = flat & 15;
    float4 v = *(const float4*)(F + (size_t)(m0 + m) * D_DIM + d0 + dq * 4);
    t[(dq * 4 + 0) * 69 + m] = v.x;
    t[(dq * 4 + 1) * 69 + m] = v.y;
    t[(dq * 4 + 2) * 69 + m] = v.z;
    t[(dq * 4 + 3) * 69 + m] = v.w;
  }
  __syncthreads();
#pragma unroll
  for (int q = 0; q < 2; q++) {
    int id = q * 256 + tid;
    int d = id >> 3, c = id & 7;  // 8 lanes per d-row write 128B contiguous
    const float* row = t + d * 69 + c * 8;
    bf16x8_t o;
#pragma unroll
    for (int i = 0; i < 8; i++) o[i] = (__bf16)row[i];
    *(bf16x8_t*)(Ft + (size_t)(d0 + d) * M_FACTS + m0 + c * 8) = o;
  }
}

// =========================================================================
// GEMM1 fast: energy = Eh*Fh^T + Eh*Fl^T + El*Fh^T, m97-style async staging.
// row_base allows banded launches (profil. visibility + unchanged perf).
// =========================================================================
__global__ __launch_bounds__(256) void gemm1_fast(const __bf16* __restrict__ Eh,
                                                  const __bf16* __restrict__ El,
                                                  const __bf16* __restrict__ Fh,
                                                  const __bf16* __restrict__ Fl,
                                                  float* __restrict__ C,
                                                  int row_base) {
  __shared__ __bf16 sAh[BM * BK], sAl[BM * BK], sBh[BN * BK], sBl[BN * BK];
  const int tid = threadIdx.x;
  const int wave = tid >> 6, lane = tid & 63;
  const int row0 = row_base + blockIdx.x * BM, col0 = blockIdx.y * BN;
  const int wm = wave >> 1, wn = wave & 1;
  const int lrow = lane & 15, quad = lane >> 4;

  f32x4_t acc[4][4];
#pragma unroll
  for (int i = 0; i < 4; i++)
#pragma unroll
    for (int j = 0; j < 4; j++) acc[i][j] = (f32x4_t){0.f, 0.f, 0.f, 0.f};

  for (int k0 = 0; k0 < D_DIM; k0 += BK) {
#pragma unroll
    for (int r = 0; r < 2; r++) {
      int c = (r * 4 + wave) * 64 + lane;  // 16B chunk id, 0..511
      int row = c >> 2;
      int ko = (c & 3) << 3;
      size_t ga = (size_t)(row0 + row) * D_DIM + k0 + ko;
      size_t gb = (size_t)(col0 + row) * D_DIM + k0 + ko;
      gload_lds16(Eh + ga, sAh + c * 8);
      gload_lds16(El + ga, sAl + c * 8);
      gload_lds16(Fh + gb, sBh + c * 8);
      gload_lds16(Fl + gb, sBl + c * 8);
    }
    __syncthreads();

    bf16x8_t ah[4], al[4], bh[4], bl[4];
#pragma unroll
    for (int i = 0; i < 4; i++) {
      int ra = (wm * 64 + i * 16 + lrow) * BK + quad * 8;
      ah[i] = *(const bf16x8_t*)(sAh + ra);
      al[i] = *(const bf16x8_t*)(sAl + ra);
      int rb = (wn * 64 + i * 16 + lrow) * BK + quad * 8;
      bh[i] = *(const bf16x8_t*)(sBh + rb);
      bl[i] = *(const bf16x8_t*)(sBl + rb);
    }
#pragma unroll
    for (int i = 0; i < 4; i++)
#pragma unroll
      for (int j = 0; j < 4; j++) {
        acc[i][j] = __builtin_amdgcn_mfma_f32_16x16x32_bf16(ah[i], bh[j], acc[i][j], 0, 0, 0);
        acc[i][j] = __builtin_amdgcn_mfma_f32_16x16x32_bf16(ah[i], bl[j], acc[i][j], 0, 0, 0);
        acc[i][j] = __builtin_amdgcn_mfma_f32_16x16x32_bf16(al[i], bh[j], acc[i][j], 0, 0, 0);
      }
    __syncthreads();
  }

#pragma unroll
  for (int i = 0; i < 4; i++) {
    int rbase = row0 + wm * 64 + i * 16 + quad * 4;
#pragma unroll
    for (int j = 0; j < 4; j++) {
      int c = col0 + wn * 64 + j * 16 + lrow;
#pragma unroll
      for (int r = 0; r < 4; r++) C[(size_t)(rbase + r) * M_FACTS + c] = acc[i][j][r];
    }
  }
}

// =========================================================================
// GEMM2 register-staged double buffer: O[out_row0+n][d] = sum_m Wb[n][m]*Ft[d][m]
// Global->VGPR loads issued ~1.5 iterations ahead; VGPR->LDS ds_write between
// two barriers. BK=32, m97 LDS layout (64B rows, proven banking). Compiler
// tracks reg deps exactly -> prefetch loads stay in flight across barriers.
// =========================================================================
__global__ __launch_bounds__(256) void gemm2_reg(const __bf16* __restrict__ Wb,
                                                 const __bf16* __restrict__ Ft,
                                                 float* __restrict__ O,
                                                 int out_row0) {
  __shared__ __bf16 sW[2][BM * BK];
  __shared__ __bf16 sF[2][BN * BK];
  const int tid = threadIdx.x;
  const int wave = tid >> 6, lane = tid & 63;
  const int col0 = blockIdx.x * BN;  // d tile (col-fast: XCD per col for L2)
  const int row0 = blockIdx.y * BM;  // n tile (chunk-local)
  const int wm = wave >> 1, wn = wave & 1;
  const int lrow = lane & 15, quad = lane >> 4;

  // Staging map: 512 chunks of 16B per array; thread handles id0 and id0+256.
  // LDS offset = id*8 elems == (id>>2)*BK + (id&3)*8  (row-major, 64B rows).
  const int id0 = wave * 64 + lane;
  const int r0 = id0 >> 2, c0 = (id0 & 3) << 3;
  const int id1 = id0 + 256;
  const int r1 = id1 >> 2, c1 = (id1 & 3) << 3;

  const __bf16* gW = Wb + (size_t)row0 * M_FACTS;
  const __bf16* gF = Ft + (size_t)col0 * M_FACTS;

  f32x4_t acc[4][4];
#pragma unroll
  for (int i = 0; i < 4; i++)
#pragma unroll
    for (int j = 0; j < 4; j++) acc[i][j] = (f32x4_t){0.f, 0.f, 0.f, 0.f};

  bf16x8_t rW0, rW1, rF0, rF1;
  // ---- tile 0 -> regs -> LDS buf0
  rW0 = *(const bf16x8_t*)(gW + (size_t)r0 * M_FACTS + c0);
  rW1 = *(const bf16x8_t*)(gW + (size_t)r1 * M_FACTS + c1);
  rF0 = *(const bf16x8_t*)(gF + (size_t)r0 * M_FACTS + c0);
  rF1 = *(const bf16x8_t*)(gF + (size_t)r1 * M_FACTS + c1);
  *(bf16x8_t*)(&sW[0][id0 * 8]) = rW0;
  *(bf16x8_t*)(&sW[0][id1 * 8]) = rW1;
  *(bf16x8_t*)(&sF[0][id0 * 8]) = rF0;
  *(bf16x8_t*)(&sF[0][id1 * 8]) = rF1;
  // ---- prefetch tile 1 -> regs
  rW0 = *(const bf16x8_t*)(gW + (size_t)r0 * M_FACTS + BK + c0);
  rW1 = *(const bf16x8_t*)(gW + (size_t)r1 * M_FACTS + BK + c1);
  rF0 = *(const bf16x8_t*)(gF + (size_t)r0 * M_FACTS + BK + c0);
  rF1 = *(const bf16x8_t*)(gF + (size_t)r1 * M_FACTS + BK + c1);
  __syncthreads();

  const int NT = M_FACTS / BK;  // 256
  for (int it = 0; it < NT; it++) {
    const int cur = it & 1;
    bf16x8_t a[4], b[4];
#pragma unroll
    for (int i = 0; i < 4; i++) {
      a[i] = *(const bf16x8_t*)(&sW[cur][(wm * 64 + i * 16 + lrow) * BK + quad * 8]);
      b[i] = *(const bf16x8_t*)(&sF[cur][(wn * 64 + i * 16 + lrow) * BK + quad * 8]);
    }
#pragma unroll
    for (int i = 0; i < 4; i++)
#pragma unroll
      for (int j = 0; j < 4; j++)
        acc[i][j] = __builtin_amdgcn_mfma_f32_16x16x32_bf16(a[i], b[j], acc[i][j], 0, 0, 0);

    __syncthreads();  // A: all reads of buf[cur] done
    if (it + 1 < NT) {
      const int nxt = cur ^ 1;
      *(bf16x8_t*)(&sW[nxt][id0 * 8]) = rW0;  // tile it+1 (waits its own loads)
      *(bf16x8_t*)(&sW[nxt][id1 * 8]) = rW1;
      *(bf16x8_t*)(&sF[nxt][id0 * 8]) = rF0;
      *(bf16x8_t*)(&sF[nxt][id1 * 8]) = rF1;
      if (it + 2 < NT) {
        const int ko = (it + 2) * BK;
        rW0 = *(const bf16x8_t*)(gW + (size_t)r0 * M_FACTS + ko + c0);
        rW1 = *(const bf16x8_t*)(gW + (size_t)r1 * M_FACTS + ko + c1);
        rF0 = *(const bf16x8_t*)(gF + (size_t)r0 * M_FACTS + ko + c0);
        rF1 = *(const bf16x8_t*)(gF + (size_t)r1 * M_FACTS + ko + c1);
      }
      __syncthreads();  // B: buf[nxt] visible before iter it+1 reads it
    }
  }

#pragma unroll
  for (int i = 0; i < 4; i++) {
    int rbase = out_row0 + row0 + wm * 64 + i * 16 + quad * 4;
#pragma unroll
    for (int j = 0; j < 4; j++) {
      int c = col0 + wn * 64 + j * 16 + lrow;
#pragma unroll
      for (int r = 0; r < 4; r++) O[(size_t)(rbase + r) * D_DIM + c] = acc[i][j][r];
    }
  }
}

// GEMM2 mid fallback: A = W fp32 (convert in staging), B = Ft via async.
__global__ __launch_bounds__(256) void gemm2_mid(const float* __restrict__ W,
                                                 const __bf16* __restrict__ Ft,
                                                 float* __restrict__ O) {
  __shared__ __bf16 sW[BM * BK], sF[BN * BK];
  const int tid = threadIdx.x;
  const int wave = tid >> 6, lane = tid & 63;
  const int row0 = blockIdx.x * BM, col0 = blockIdx.y * BN;
  const int wm = wave >> 1, wn = wave & 1;
  const int lrow = lane & 15, quad = lane >> 4;

  f32x4_t acc[4][4];
#pragma unroll
  for (int i = 0; i < 4; i++)
#pragma unroll
    for (int j = 0; j < 4; j++) acc[i][j] = (f32x4_t){0.f, 0.f, 0.f, 0.f};

  for (int k0 = 0; k0 < M_FACTS; k0 += BK) {
#pragma unroll
    for (int r = 0; r < 2; r++) {
      int c = (r * 4 + wave) * 64 + lane;
      int row = c >> 2;
      int ko = (c & 3) << 3;
      gload_lds16(Ft + (size_t)(col0 + row) * M_FACTS + k0 + ko, sF + c * 8);
    }
#pragma unroll
    for (int it = 0; it < 4; it++) {
      int flat = it * 256 + tid;
      int r = flat >> 3, q = flat & 7;
      float4 v = *(const float4*)(W + (size_t)(row0 + r) * M_FACTS + k0 + q * 4);
      bf16x4_t h;
      h[0] = (__bf16)v.x;
      h[1] = (__bf16)v.y;
      h[2] = (__bf16)v.z;
      h[3] = (__bf16)v.w;
      *(bf16x4_t*)(sW + r * BK + q * 4) = h;
    }
    __syncthreads();

    bf16x8_t a[4], b[4];
#pragma unroll
    for (int i = 0; i < 4; i++) {
      a[i] = *(const bf16x8_t*)(sW + (wm * 64 + i * 16 + lrow) * BK + quad * 8);
      b[i] = *(const bf16x8_t*)(sF + (wn * 64 + i * 16 + lrow) * BK + quad * 8);
    }
#pragma unroll
    for (int i = 0; i < 4; i++)
#pragma unroll
      for (int j = 0; j < 4; j++)
        acc[i][j] = __builtin_amdgcn_mfma_f32_16x16x32_bf16(a[i], b[j], acc[i][j], 0, 0, 0);
    __syncthreads();
  }

#pragma unroll
  for (int i = 0; i < 4; i++) {
    int rbase = row0 + wm * 64 + i * 16 + quad * 4;
#pragma unroll
    for (int j = 0; j < 4; j++) {
      int c = col0 + wn * 64 + j * 16 + lrow;
#pragma unroll
      for (int r = 0; r < 4; r++) O[(size_t)(rbase + r) * D_DIM + c] = acc[i][j][r];
    }
  }
}

// =========================================================================
// Softmax (optionally emitting bf16 copy of weights)
// =========================================================================
template <bool EMIT_BF16>
__global__ __launch_bounds__(256) void softmax_rows_t(float* __restrict__ W,
                                                      __bf16* __restrict__ Wb) {
  __shared__ float red[8];
  const int tid = threadIdx.x;
  float* p = W + (size_t)blockIdx.x * M_FACTS;

  float4 v[8];
  float mx = -3.4e38f;
#pragma unroll
  for (int i = 0; i < 8; i++) {
    v[i] = *(const float4*)(p + (size_t)(i * 256 + tid) * 4);
    mx = fmaxf(mx, fmaxf(fmaxf(v[i].x, v[i].y), fmaxf(v[i].z, v[i].w)));
  }
#pragma unroll
  for (int off = 32; off >= 1; off >>= 1) mx = fmaxf(mx, __shfl_xor(mx, off));
  const int wave = tid >> 6, lane = tid & 63;
  if (lane == 0) red[wave] = mx;
  __syncthreads();
  mx = fmaxf(fmaxf(red[0], red[1]), fmaxf(red[2], red[3]));

  float s = 0.f;
#pragma unroll
  for (int i = 0; i < 8; i++) {
    v[i].x = __expf(v[i].x - mx);
    v[i].y = __expf(v[i].y - mx);
    v[i].z = __expf(v[i].z - mx);
    v[i].w = __expf(v[i].w - mx);
    s += v[i].x + v[i].y + v[i].z + v[i].w;
  }
#pragma unroll
  for (int off = 32; off >= 1; off >>= 1) s += __shfl_xor(s, off);
  if (lane == 0) red[4 + wave] = s;
  __syncthreads();
  s = red[4] + red[5] + red[6] + red[7];
  float inv = 1.0f / s;
  __bf16* pb = EMIT_BF16 ? (Wb + (size_t)blockIdx.x * M_FACTS) : nullptr;
#pragma unroll
  for (int i = 0; i < 8; i++) {
    v[i].x *= inv;
    v[i].y *= inv;
    v[i].z *= inv;
    v[i].w *= inv;
    *(float4*)(p + (size_t)(i * 256 + tid) * 4) = v[i];
    if (EMIT_BF16) {
      bf16x4_t h;
      h[0] = (__bf16)v[i].x;
      h[1] = (__bf16)v[i].y;
      h[2] = (__bf16)v[i].z;
      h[3] = (__bf16)v[i].w;
      *(bf16x4_t*)(pb + (size_t)(i * 256 + tid) * 4) = h;
    }
  }
}

// =========================================================================
// Lowest-tier fallback kernels (ws < 80 MiB)
// =========================================================================
__global__ __launch_bounds__(256) void gemm1_energy(const float* __restrict__ A,
                                                    const float* __restrict__ B,
                                                    float* __restrict__ C) {
  __shared__ __align__(16) __bf16 sAh[BM * PADK];
  __shared__ __align__(16) __bf16 sAl[BM * PADK];
  __shared__ __align__(16) __bf16 sBh[BN * PADK];
  __shared__ __align__(16) __bf16 sBl[BN * PADK];

  const int tid = threadIdx.x;
  const int row0 = blockIdx.x * BM, col0 = blockIdx.y * BN;
  const int wave = tid >> 6, lane = tid & 63;
  const int wm = wave >> 1, wn = wave & 1;
  const int lrow = lane & 15, quad = lane >> 4;

  f32x4_t acc[4][4];
#pragma unroll
  for (int i = 0; i < 4; i++)
#pragma unroll
    for (int j = 0; j < 4; j++) acc[i][j] = (f32x4_t){0.f, 0.f, 0.f, 0.f};

  for (int k0 = 0; k0 < D_DIM; k0 += BK) {
    __syncthreads();
#pragma unroll
    for (int it = 0; it < 4; it++) {
      int flat = it * 256 + tid;
      int r = flat >> 3, kq = flat & 7;
      float4 va = *(const float4*)(A + (size_t)(row0 + r) * D_DIM + k0 + kq * 4);
      float4 vb = *(const float4*)(B + (size_t)(col0 + r) * D_DIM + k0 + kq * 4);
      float fa[4] = {va.x, va.y, va.z, va.w};
      float fb[4] = {vb.x, vb.y, vb.z, vb.w};
      bf16x4_t ah, al, bh, bl;
#pragma unroll
      for (int q = 0; q < 4; q++) {
        __bf16 h = (__bf16)fa[q];
        ah[q] = h;
        al[q] = (__bf16)(fa[q] - (float)h);
        __bf16 g = (__bf16)fb[q];
        bh[q] = g;
        bl[q] = (__bf16)(fb[q] - (float)g);
      }
      *(bf16x4_t*)(sAh + r * PADK + kq * 4) = ah;
      *(bf16x4_t*)(sAl + r * PADK + kq * 4) = al;
      *(bf16x4_t*)(sBh + r * PADK + kq * 4) = bh;
      *(bf16x4_t*)(sBl + r * PADK + kq * 4) = bl;
    }
    __syncthreads();

    bf16x8_t a_h[4], a_l[4], b_h[4], b_l[4];
#pragma unroll
    for (int i = 0; i < 4; i++) {
      int ra = wm * 64 + i * 16 + lrow;
      a_h[i] = *(const bf16x8_t*)(sAh + ra * PADK + quad * 8);
      a_l[i] = *(const bf16x8_t*)(sAl + ra * PADK + quad * 8);
      int rb = wn * 64 + i * 16 + lrow;
      b_h[i] = *(const bf16x8_t*)(sBh + rb * PADK + quad * 8);
      b_l[i] = *(const bf16x8_t*)(sBl + rb * PADK + quad * 8);
    }
#pragma unroll
    for (int i = 0; i < 4; i++)
#pragma unroll
      for (int j = 0; j < 4; j++) {
        acc[i][j] = __builtin_amdgcn_mfma_f32_16x16x32_bf16(a_h[i], b_h[j], acc[i][j], 0, 0, 0);
        acc[i][j] = __builtin_amdgcn_mfma_f32_16x16x32_bf16(a_h[i], b_l[j], acc[i][j], 0, 0, 0);
        acc[i][j] = __builtin_amdgcn_mfma_f32_16x16x32_bf16(a_l[i], b_h[j], acc[i][j], 0, 0, 0);
      }
  }

#pragma unroll
  for (int i = 0; i < 4; i++) {
    int rbase = row0 + wm * 64 + i * 16 + quad * 4;
#pragma unroll
    for (int j = 0; j < 4; j++) {
      int c = col0 + wn * 64 + j * 16 + lrow;
#pragma unroll
      for (int r = 0; r < 4; r++) C[(size_t)(rbase + r) * M_FACTS + c] = acc[i][j][r];
    }
  }
}

__global__ __launch_bounds__(256) void gemm2_out(const float* __restrict__ W,
                                                 const float* __restrict__ F,
                                                 float* __restrict__ O) {
  __shared__ __align__(16) __bf16 sW[BM * PADK];
  __shared__ __align__(16) __bf16 sFt[BN * PADK];

  const int tid = threadIdx.x;
  const int row0 = blockIdx.x * BM, col0 = blockIdx.y * BN;
  const int wave = tid >> 6, lane = tid & 63;
  const int wm = wave >> 1, wn = wave & 1;
  const int lrow = lane & 15, quad = lane >> 4;

  f32x4_t acc[4][4];
#pragma unroll
  for (int i = 0; i < 4; i++)
#pragma unroll
    for (int j = 0; j < 4; j++) acc[i][j] = (f32x4_t){0.f, 0.f, 0.f, 0.f};

  for (int k0 = 0; k0 < M_FACTS; k0 += BK) {
    __syncthreads();
#pragma unroll
    for (int it = 0; it < 4; it++) {
      int flat = it * 256 + tid;
      int r = flat >> 3, kq = flat & 7;
      float4 v = *(const float4*)(W + (size_t)(row0 + r) * M_FACTS + k0 + kq * 4);
      bf16x4_t h;
      h[0] = (__bf16)v.x;
      h[1] = (__bf16)v.y;
      h[2] = (__bf16)v.z;
      h[3] = (__bf16)v.w;
      *(bf16x4_t*)(sW + r * PADK + kq * 4) = h;
    }
#pragma unroll
    for (int it = 0; it < 4; it++) {
      int flat = it * 256 + tid;
      int m = flat >> 5, dq = flat & 31;
      float4 v = *(const float4*)(F + (size_t)(k0 + m) * D_DIM + col0 + dq * 4);
      sFt[(dq * 4 + 0) * PADK + m] = (__bf16)v.x;
      sFt[(dq * 4 + 1) * PADK + m] = (__bf16)v.y;
      sFt[(dq * 4 + 2) * PADK + m] = (__bf16)v.z;
      sFt[(dq * 4 + 3) * PADK + m] = (__bf16)v.w;
    }
    __syncthreads();

    bf16x8_t a[4], b[4];
#pragma unroll
    for (int i = 0; i < 4; i++) {
      a[i] = *(const bf16x8_t*)(sW + (wm * 64 + i * 16 + lrow) * PADK + quad * 8);
      b[i] = *(const bf16x8_t*)(sFt + (wn * 64 + i * 16 + lrow) * PADK + quad * 8);
    }
#pragma unroll
    for (int i = 0; i < 4; i++)
#pragma unroll
      for (int j = 0; j < 4; j++)
        acc[i][j] = __builtin_amdgcn_mfma_f32_16x16x32_bf16(a[i], b[j], acc[i][j], 0, 0, 0);
  }

#pragma unroll
  for (int i = 0; i < 4; i++) {
    int rbase = row0 + wm * 64 + i * 16 + quad * 4;
#pragma unroll
    for (int j = 0; j < 4; j++) {
      int c = col0 + wn * 64 + j * 16 + lrow;
#pragma unroll
      for (int r = 0; r < 4; r++) O[(size_t)(rbase + r) * D_DIM + c] = acc[i][j][r];
    }
  }
}

// =========================================================================
extern "C" void kernel_launch(void* const* d_in, const int* in_sizes, int n_in,
                              void* d_out, int out_size, void* d_ws, size_t ws_size,
                              hipStream_t stream) {
  const float* E = (const float*)d_in[0];  // [N, D]
  const float* F = (const float*)d_in[1];  // [M, D]
  float* outputs = (float*)d_out;                           // [N, D]
  float* weights = (float*)d_out + (size_t)N_ROWS * D_DIM;  // [N, M]

  const size_t MB = 1ull << 20;
  char* ws = (char*)d_ws;

  const bool t1 = ws_size >= 144 * MB;
  const bool t2 = !t1 && ws_size >= 80 * MB;
  const bool hasFtOnly = !t1 && !t2 && ws_size >= 16 * MB;

  if (t1 || t2) {
    __bf16* Ft = (__bf16*)(ws + 0 * MB);
    __bf16* Eh = (__bf16*)(ws + 16 * MB);
    __bf16* El = (__bf16*)(ws + 32 * MB);
    __bf16* Fh = (__bf16*)(ws + 48 * MB);
    __bf16* Fl = (__bf16*)(ws + 64 * MB);
    __bf16* Wb = (__bf16*)(ws + 16 * MB);  // aliases dead splits after gemm1

    transpose_f_bf16<<<dim3(M_FACTS / 64, D_DIM / 64), 256, 0, stream>>>(F, Ft);
    split_hi_lo<<<dim3((N_ROWS * D_DIM) / 1024), 256, 0, stream>>>(E, Eh, El);
    split_hi_lo<<<dim3((M_FACTS * D_DIM) / 1024), 256, 0, stream>>>(F, Fh, Fl);
    // 8 row-bands: per-dispatch visibility in rocprof top-5
    for (int b = 0; b < 8; b++) {
      gemm1_fast<<<dim3(8, M_FACTS / BN), 256, 0, stream>>>(Eh, El, Fh, Fl, weights,
                                                            b * (N_ROWS / 8));
    }

    if (t1) {
      softmax_rows_t<true><<<dim3(N_ROWS), 256, 0, stream>>>(weights, Wb);
      gemm2_reg<<<dim3(D_DIM / BN, N_ROWS / BM), 256, 0, stream>>>(Wb, Ft, outputs, 0);
    } else {
      const int HALF = N_ROWS / 2;
      for (int h = 0; h < 2; h++) {
        float* Wchunk = weights + (size_t)h * HALF * M_FACTS;
        softmax_rows_t<true><<<dim3(HALF), 256, 0, stream>>>(Wchunk, Wb);
        gemm2_reg<<<dim3(D_DIM / BN, HALF / BM), 256, 0, stream>>>(Wb, Ft, outputs, h * HALF);
      }
    }
  } else {
    __bf16* Ft = (__bf16*)ws;  // 16 MiB
    if (hasFtOnly) {
      transpose_f_bf16<<<dim3(M_FACTS / 64, D_DIM / 64), 256, 0, stream>>>(F, Ft);
    }
    gemm1_energy<<<dim3(N_ROWS / BM, M_FACTS / BN), 256, 0, stream>>>(E, F, weights);
    softmax_rows_t<false><<<dim3(N_ROWS), 256, 0, stream>>>(weights, nullptr);
    if (hasFtOnly) {
      gemm2_mid<<<dim3(N_ROWS / BM, D_DIM / BN), 256, 0, stream>>>(weights, Ft, outputs);
    } else {
      gemm2_out<<<dim3(N_ROWS / BM, D_DIM / BN), 256, 0, stream>>>(weights, F, outputs);
    }
  }
}

// Round 6
// 966.000 us; speedup vs baseline: 1.1223x; 1.1223x over previous
//
#include <hip/hip_runtime.h>
#include <hip/hip_bf16.h>
#include <math.h>
#include <stdint.h>

#define N_ROWS 8192
#define M_FACTS 8192
#define D_DIM 1024

typedef __bf16 bf16x8_t __attribute__((ext_vector_type(8)));
typedef __bf16 bf16x4_t __attribute__((ext_vector_type(4)));
typedef float f32x4_t __attribute__((ext_vector_type(4)));

#define BM 128
#define BN 128
#define BK 32
#define PADK 40  // legacy padded stride for fallback kernels

// Async global->LDS, 16B per lane. LDS dest = wave-uniform base + lane*16.
__device__ __forceinline__ void gload_lds16(const void* g, void* lds) {
  __builtin_amdgcn_global_load_lds(
      (__attribute__((address_space(1))) void*)(uintptr_t)g,
      (__attribute__((address_space(3))) void*)(uint32_t)(uintptr_t)lds,
      16, 0, 0);
}

// =========================================================================
// Precompute kernels
// =========================================================================

__global__ __launch_bounds__(256) void split_hi_lo(const float* __restrict__ X,
                                                   __bf16* __restrict__ H,
                                                   __bf16* __restrict__ L) {
  int i = blockIdx.x * 256 + threadIdx.x;
  float4 v = ((const float4*)X)[i];
  float f[4] = {v.x, v.y, v.z, v.w};
  bf16x4_t h, l;
#pragma unroll
  for (int q = 0; q < 4; q++) {
    __bf16 hh = (__bf16)f[q];
    h[q] = hh;
    l[q] = (__bf16)(f[q] - (float)hh);
  }
  ((bf16x4_t*)H)[i] = h;
  ((bf16x4_t*)L)[i] = l;
}

// F fp32 [M][D] -> Ft bf16 [D][M]. 64x64 tiles; fp32 LDS tile stride 69
// (<=2-way banks both phases); global writes coalesced 128B per 8 lanes.
__global__ __launch_bounds__(256) void transpose_f_bf16(const float* __restrict__ F,
                                                        __bf16* __restrict__ Ft) {
  __shared__ float t[64 * 69];
  const int tid = threadIdx.x;
  const int m0 = blockIdx.x * 64, d0 = blockIdx.y * 64;
#pragma unroll
  for (int p = 0; p < 4; p++) {
    int flat = p * 256 + tid;
    int m = flat >> 4, dq = flat & 15;
    float4 v = *(const float4*)(F + (size_t)(m0 + m) * D_DIM + d0 + dq * 4);
    t[(dq * 4 + 0) * 69 + m] = v.x;
    t[(dq * 4 + 1) * 69 + m] = v.y;
    t[(dq * 4 + 2) * 69 + m] = v.z;
    t[(dq * 4 + 3) * 69 + m] = v.w;
  }
  __syncthreads();
#pragma unroll
  for (int q = 0; q < 2; q++) {
    int id = q * 256 + tid;
    int d = id >> 3, c = id & 7;  // 8 lanes per d-row write 128B contiguous
    const float* row = t + d * 69 + c * 8;
    bf16x8_t o;
#pragma unroll
    for (int i = 0; i < 8; i++) o[i] = (__bf16)row[i];
    *(bf16x8_t*)(Ft + (size_t)(d0 + d) * M_FACTS + m0 + c * 8) = o;
  }
}

// =========================================================================
// GEMM1 fast: energy = Eh*Fh^T + Eh*Fl^T + El*Fh^T, m97-style async staging.
// =========================================================================
__global__ __launch_bounds__(256) void gemm1_fast(const __bf16* __restrict__ Eh,
                                                  const __bf16* __restrict__ El,
                                                  const __bf16* __restrict__ Fh,
                                                  const __bf16* __restrict__ Fl,
                                                  float* __restrict__ C,
                                                  int row_base) {
  __shared__ __bf16 sAh[BM * BK], sAl[BM * BK], sBh[BN * BK], sBl[BN * BK];
  const int tid = threadIdx.x;
  const int wave = tid >> 6, lane = tid & 63;
  const int row0 = row_base + blockIdx.x * BM, col0 = blockIdx.y * BN;
  const int wm = wave >> 1, wn = wave & 1;
  const int lrow = lane & 15, quad = lane >> 4;

  f32x4_t acc[4][4];
#pragma unroll
  for (int i = 0; i < 4; i++)
#pragma unroll
    for (int j = 0; j < 4; j++) acc[i][j] = (f32x4_t){0.f, 0.f, 0.f, 0.f};

  for (int k0 = 0; k0 < D_DIM; k0 += BK) {
#pragma unroll
    for (int r = 0; r < 2; r++) {
      int c = (r * 4 + wave) * 64 + lane;  // 16B chunk id, 0..511
      int row = c >> 2;
      int ko = (c & 3) << 3;
      size_t ga = (size_t)(row0 + row) * D_DIM + k0 + ko;
      size_t gb = (size_t)(col0 + row) * D_DIM + k0 + ko;
      gload_lds16(Eh + ga, sAh + c * 8);
      gload_lds16(El + ga, sAl + c * 8);
      gload_lds16(Fh + gb, sBh + c * 8);
      gload_lds16(Fl + gb, sBl + c * 8);
    }
    __syncthreads();

    bf16x8_t ah[4], al[4], bh[4], bl[4];
#pragma unroll
    for (int i = 0; i < 4; i++) {
      int ra = (wm * 64 + i * 16 + lrow) * BK + quad * 8;
      ah[i] = *(const bf16x8_t*)(sAh + ra);
      al[i] = *(const bf16x8_t*)(sAl + ra);
      int rb = (wn * 64 + i * 16 + lrow) * BK + quad * 8;
      bh[i] = *(const bf16x8_t*)(sBh + rb);
      bl[i] = *(const bf16x8_t*)(sBl + rb);
    }
#pragma unroll
    for (int i = 0; i < 4; i++)
#pragma unroll
      for (int j = 0; j < 4; j++) {
        acc[i][j] = __builtin_amdgcn_mfma_f32_16x16x32_bf16(ah[i], bh[j], acc[i][j], 0, 0, 0);
        acc[i][j] = __builtin_amdgcn_mfma_f32_16x16x32_bf16(ah[i], bl[j], acc[i][j], 0, 0, 0);
        acc[i][j] = __builtin_amdgcn_mfma_f32_16x16x32_bf16(al[i], bh[j], acc[i][j], 0, 0, 0);
      }
    __syncthreads();
  }

#pragma unroll
  for (int i = 0; i < 4; i++) {
    int rbase = row0 + wm * 64 + i * 16 + quad * 4;
#pragma unroll
    for (int j = 0; j < 4; j++) {
      int c = col0 + wn * 64 + j * 16 + lrow;
#pragma unroll
      for (int r = 0; r < 4; r++) C[(size_t)(rbase + r) * M_FACTS + c] = acc[i][j][r];
    }
  }
}

// =========================================================================
// GEMM2 register-staged double buffer. Grid = (n-tiles, d-tiles): linear
// block id = n + 64*d -> XCD = n%8, so the 8 d-blocks sharing one Wb
// row-slice (2 MB, fits 4 MB XCD L2) co-locate on ONE XCD and dispatch
// together -> Wb fetched from HBM ~once instead of ~5x.
// =========================================================================
__global__ __launch_bounds__(256) void gemm2_reg(const __bf16* __restrict__ Wb,
                                                 const __bf16* __restrict__ Ft,
                                                 float* __restrict__ O,
                                                 int out_row0) {
  __shared__ __bf16 sW[2][BM * BK];
  __shared__ __bf16 sF[2][BN * BK];
  const int tid = threadIdx.x;
  const int wave = tid >> 6, lane = tid & 63;
  const int row0 = blockIdx.x * BM;  // n tile (fast axis -> XCD = n%8)
  const int col0 = blockIdx.y * BN;  // d tile
  const int wm = wave >> 1, wn = wave & 1;
  const int lrow = lane & 15, quad = lane >> 4;

  // Staging map: 512 chunks of 16B per array; thread handles id0 and id0+256.
  const int id0 = wave * 64 + lane;
  const int r0 = id0 >> 2, c0 = (id0 & 3) << 3;
  const int id1 = id0 + 256;
  const int r1 = id1 >> 2, c1 = (id1 & 3) << 3;

  const __bf16* gW = Wb + (size_t)row0 * M_FACTS;
  const __bf16* gF = Ft + (size_t)col0 * M_FACTS;

  f32x4_t acc[4][4];
#pragma unroll
  for (int i = 0; i < 4; i++)
#pragma unroll
    for (int j = 0; j < 4; j++) acc[i][j] = (f32x4_t){0.f, 0.f, 0.f, 0.f};

  bf16x8_t rW0, rW1, rF0, rF1;
  // ---- tile 0 -> regs -> LDS buf0
  rW0 = *(const bf16x8_t*)(gW + (size_t)r0 * M_FACTS + c0);
  rW1 = *(const bf16x8_t*)(gW + (size_t)r1 * M_FACTS + c1);
  rF0 = *(const bf16x8_t*)(gF + (size_t)r0 * M_FACTS + c0);
  rF1 = *(const bf16x8_t*)(gF + (size_t)r1 * M_FACTS + c1);
  *(bf16x8_t*)(&sW[0][id0 * 8]) = rW0;
  *(bf16x8_t*)(&sW[0][id1 * 8]) = rW1;
  *(bf16x8_t*)(&sF[0][id0 * 8]) = rF0;
  *(bf16x8_t*)(&sF[0][id1 * 8]) = rF1;
  // ---- prefetch tile 1 -> regs
  rW0 = *(const bf16x8_t*)(gW + (size_t)r0 * M_FACTS + BK + c0);
  rW1 = *(const bf16x8_t*)(gW + (size_t)r1 * M_FACTS + BK + c1);
  rF0 = *(const bf16x8_t*)(gF + (size_t)r0 * M_FACTS + BK + c0);
  rF1 = *(const bf16x8_t*)(gF + (size_t)r1 * M_FACTS + BK + c1);
  __syncthreads();

  const int NT = M_FACTS / BK;  // 256
  for (int it = 0; it < NT; it++) {
    const int cur = it & 1;
    bf16x8_t a[4], b[4];
#pragma unroll
    for (int i = 0; i < 4; i++) {
      a[i] = *(const bf16x8_t*)(&sW[cur][(wm * 64 + i * 16 + lrow) * BK + quad * 8]);
      b[i] = *(const bf16x8_t*)(&sF[cur][(wn * 64 + i * 16 + lrow) * BK + quad * 8]);
    }
#pragma unroll
    for (int i = 0; i < 4; i++)
#pragma unroll
      for (int j = 0; j < 4; j++)
        acc[i][j] = __builtin_amdgcn_mfma_f32_16x16x32_bf16(a[i], b[j], acc[i][j], 0, 0, 0);

    __syncthreads();  // A: all reads of buf[cur] done
    if (it + 1 < NT) {
      const int nxt = cur ^ 1;
      *(bf16x8_t*)(&sW[nxt][id0 * 8]) = rW0;  // tile it+1 (waits its own loads)
      *(bf16x8_t*)(&sW[nxt][id1 * 8]) = rW1;
      *(bf16x8_t*)(&sF[nxt][id0 * 8]) = rF0;
      *(bf16x8_t*)(&sF[nxt][id1 * 8]) = rF1;
      if (it + 2 < NT) {
        const int ko = (it + 2) * BK;
        rW0 = *(const bf16x8_t*)(gW + (size_t)r0 * M_FACTS + ko + c0);
        rW1 = *(const bf16x8_t*)(gW + (size_t)r1 * M_FACTS + ko + c1);
        rF0 = *(const bf16x8_t*)(gF + (size_t)r0 * M_FACTS + ko + c0);
        rF1 = *(const bf16x8_t*)(gF + (size_t)r1 * M_FACTS + ko + c1);
      }
      __syncthreads();  // B: buf[nxt] visible before iter it+1 reads it
    }
  }

#pragma unroll
  for (int i = 0; i < 4; i++) {
    int rbase = out_row0 + row0 + wm * 64 + i * 16 + quad * 4;
#pragma unroll
    for (int j = 0; j < 4; j++) {
      int c = col0 + wn * 64 + j * 16 + lrow;
#pragma unroll
      for (int r = 0; r < 4; r++) O[(size_t)(rbase + r) * D_DIM + c] = acc[i][j][r];
    }
  }
}

// GEMM2 mid fallback: A = W fp32 (convert in staging), B = Ft via async.
__global__ __launch_bounds__(256) void gemm2_mid(const float* __restrict__ W,
                                                 const __bf16* __restrict__ Ft,
                                                 float* __restrict__ O) {
  __shared__ __bf16 sW[BM * BK], sF[BN * BK];
  const int tid = threadIdx.x;
  const int wave = tid >> 6, lane = tid & 63;
  const int row0 = blockIdx.x * BM, col0 = blockIdx.y * BN;
  const int wm = wave >> 1, wn = wave & 1;
  const int lrow = lane & 15, quad = lane >> 4;

  f32x4_t acc[4][4];
#pragma unroll
  for (int i = 0; i < 4; i++)
#pragma unroll
    for (int j = 0; j < 4; j++) acc[i][j] = (f32x4_t){0.f, 0.f, 0.f, 0.f};

  for (int k0 = 0; k0 < M_FACTS; k0 += BK) {
#pragma unroll
    for (int r = 0; r < 2; r++) {
      int c = (r * 4 + wave) * 64 + lane;
      int row = c >> 2;
      int ko = (c & 3) << 3;
      gload_lds16(Ft + (size_t)(col0 + row) * M_FACTS + k0 + ko, sF + c * 8);
    }
#pragma unroll
    for (int it = 0; it < 4; it++) {
      int flat = it * 256 + tid;
      int r = flat >> 3, q = flat & 7;
      float4 v = *(const float4*)(W + (size_t)(row0 + r) * M_FACTS + k0 + q * 4);
      bf16x4_t h;
      h[0] = (__bf16)v.x;
      h[1] = (__bf16)v.y;
      h[2] = (__bf16)v.z;
      h[3] = (__bf16)v.w;
      *(bf16x4_t*)(sW + r * BK + q * 4) = h;
    }
    __syncthreads();

    bf16x8_t a[4], b[4];
#pragma unroll
    for (int i = 0; i < 4; i++) {
      a[i] = *(const bf16x8_t*)(sW + (wm * 64 + i * 16 + lrow) * BK + quad * 8);
      b[i] = *(const bf16x8_t*)(sF + (wn * 64 + i * 16 + lrow) * BK + quad * 8);
    }
#pragma unroll
    for (int i = 0; i < 4; i++)
#pragma unroll
      for (int j = 0; j < 4; j++)
        acc[i][j] = __builtin_amdgcn_mfma_f32_16x16x32_bf16(a[i], b[j], acc[i][j], 0, 0, 0);
    __syncthreads();
  }

#pragma unroll
  for (int i = 0; i < 4; i++) {
    int rbase = row0 + wm * 64 + i * 16 + quad * 4;
#pragma unroll
    for (int j = 0; j < 4; j++) {
      int c = col0 + wn * 64 + j * 16 + lrow;
#pragma unroll
      for (int r = 0; r < 4; r++) O[(size_t)(rbase + r) * D_DIM + c] = acc[i][j][r];
    }
  }
}

// =========================================================================
// Softmax (optionally emitting bf16 copy of weights)
// =========================================================================
template <bool EMIT_BF16>
__global__ __launch_bounds__(256) void softmax_rows_t(float* __restrict__ W,
                                                      __bf16* __restrict__ Wb) {
  __shared__ float red[8];
  const int tid = threadIdx.x;
  float* p = W + (size_t)blockIdx.x * M_FACTS;

  float4 v[8];
  float mx = -3.4e38f;
#pragma unroll
  for (int i = 0; i < 8; i++) {
    v[i] = *(const float4*)(p + (size_t)(i * 256 + tid) * 4);
    mx = fmaxf(mx, fmaxf(fmaxf(v[i].x, v[i].y), fmaxf(v[i].z, v[i].w)));
  }
#pragma unroll
  for (int off = 32; off >= 1; off >>= 1) mx = fmaxf(mx, __shfl_xor(mx, off));
  const int wave = tid >> 6, lane = tid & 63;
  if (lane == 0) red[wave] = mx;
  __syncthreads();
  mx = fmaxf(fmaxf(red[0], red[1]), fmaxf(red[2], red[3]));

  float s = 0.f;
#pragma unroll
  for (int i = 0; i < 8; i++) {
    v[i].x = __expf(v[i].x - mx);
    v[i].y = __expf(v[i].y - mx);
    v[i].z = __expf(v[i].z - mx);
    v[i].w = __expf(v[i].w - mx);
    s += v[i].x + v[i].y + v[i].z + v[i].w;
  }
#pragma unroll
  for (int off = 32; off >= 1; off >>= 1) s += __shfl_xor(s, off);
  if (lane == 0) red[4 + wave] = s;
  __syncthreads();
  s = red[4] + red[5] + red[6] + red[7];
  float inv = 1.0f / s;
  __bf16* pb = EMIT_BF16 ? (Wb + (size_t)blockIdx.x * M_FACTS) : nullptr;
#pragma unroll
  for (int i = 0; i < 8; i++) {
    v[i].x *= inv;
    v[i].y *= inv;
    v[i].z *= inv;
    v[i].w *= inv;
    *(float4*)(p + (size_t)(i * 256 + tid) * 4) = v[i];
    if (EMIT_BF16) {
      bf16x4_t h;
      h[0] = (__bf16)v[i].x;
      h[1] = (__bf16)v[i].y;
      h[2] = (__bf16)v[i].z;
      h[3] = (__bf16)v[i].w;
      *(bf16x4_t*)(pb + (size_t)(i * 256 + tid) * 4) = h;
    }
  }
}

// =========================================================================
// Lowest-tier fallback kernels (ws < 80 MiB)
// =========================================================================
__global__ __launch_bounds__(256) void gemm1_energy(const float* __restrict__ A,
                                                    const float* __restrict__ B,
                                                    float* __restrict__ C) {
  __shared__ __align__(16) __bf16 sAh[BM * PADK];
  __shared__ __align__(16) __bf16 sAl[BM * PADK];
  __shared__ __align__(16) __bf16 sBh[BN * PADK];
  __shared__ __align__(16) __bf16 sBl[BN * PADK];

  const int tid = threadIdx.x;
  const int row0 = blockIdx.x * BM, col0 = blockIdx.y * BN;
  const int wave = tid >> 6, lane = tid & 63;
  const int wm = wave >> 1, wn = wave & 1;
  const int lrow = lane & 15, quad = lane >> 4;

  f32x4_t acc[4][4];
#pragma unroll
  for (int i = 0; i < 4; i++)
#pragma unroll
    for (int j = 0; j < 4; j++) acc[i][j] = (f32x4_t){0.f, 0.f, 0.f, 0.f};

  for (int k0 = 0; k0 < D_DIM; k0 += BK) {
    __syncthreads();
#pragma unroll
    for (int it = 0; it < 4; it++) {
      int flat = it * 256 + tid;
      int r = flat >> 3, kq = flat & 7;
      float4 va = *(const float4*)(A + (size_t)(row0 + r) * D_DIM + k0 + kq * 4);
      float4 vb = *(const float4*)(B + (size_t)(col0 + r) * D_DIM + k0 + kq * 4);
      float fa[4] = {va.x, va.y, va.z, va.w};
      float fb[4] = {vb.x, vb.y, vb.z, vb.w};
      bf16x4_t ah, al, bh, bl;
#pragma unroll
      for (int q = 0; q < 4; q++) {
        __bf16 h = (__bf16)fa[q];
        ah[q] = h;
        al[q] = (__bf16)(fa[q] - (float)h);
        __bf16 g = (__bf16)fb[q];
        bh[q] = g;
        bl[q] = (__bf16)(fb[q] - (float)g);
      }
      *(bf16x4_t*)(sAh + r * PADK + kq * 4) = ah;
      *(bf16x4_t*)(sAl + r * PADK + kq * 4) = al;
      *(bf16x4_t*)(sBh + r * PADK + kq * 4) = bh;
      *(bf16x4_t*)(sBl + r * PADK + kq * 4) = bl;
    }
    __syncthreads();

    bf16x8_t a_h[4], a_l[4], b_h[4], b_l[4];
#pragma unroll
    for (int i = 0; i < 4; i++) {
      int ra = wm * 64 + i * 16 + lrow;
      a_h[i] = *(const bf16x8_t*)(sAh + ra * PADK + quad * 8);
      a_l[i] = *(const bf16x8_t*)(sAl + ra * PADK + quad * 8);
      int rb = wn * 64 + i * 16 + lrow;
      b_h[i] = *(const bf16x8_t*)(sBh + rb * PADK + quad * 8);
      b_l[i] = *(const bf16x8_t*)(sBl + rb * PADK + quad * 8);
    }
#pragma unroll
    for (int i = 0; i < 4; i++)
#pragma unroll
      for (int j = 0; j < 4; j++) {
        acc[i][j] = __builtin_amdgcn_mfma_f32_16x16x32_bf16(a_h[i], b_h[j], acc[i][j], 0, 0, 0);
        acc[i][j] = __builtin_amdgcn_mfma_f32_16x16x32_bf16(a_h[i], b_l[j], acc[i][j], 0, 0, 0);
        acc[i][j] = __builtin_amdgcn_mfma_f32_16x16x32_bf16(a_l[i], b_h[j], acc[i][j], 0, 0, 0);
      }
  }

#pragma unroll
  for (int i = 0; i < 4; i++) {
    int rbase = row0 + wm * 64 + i * 16 + quad * 4;
#pragma unroll
    for (int j = 0; j < 4; j++) {
      int c = col0 + wn * 64 + j * 16 + lrow;
#pragma unroll
      for (int r = 0; r < 4; r++) C[(size_t)(rbase + r) * M_FACTS + c] = acc[i][j][r];
    }
  }
}

__global__ __launch_bounds__(256) void gemm2_out(const float* __restrict__ W,
                                                 const float* __restrict__ F,
                                                 float* __restrict__ O) {
  __shared__ __align__(16) __bf16 sW[BM * PADK];
  __shared__ __align__(16) __bf16 sFt[BN * PADK];

  const int tid = threadIdx.x;
  const int row0 = blockIdx.x * BM, col0 = blockIdx.y * BN;
  const int wave = tid >> 6, lane = tid & 63;
  const int wm = wave >> 1, wn = wave & 1;
  const int lrow = lane & 15, quad = lane >> 4;

  f32x4_t acc[4][4];
#pragma unroll
  for (int i = 0; i < 4; i++)
#pragma unroll
    for (int j = 0; j < 4; j++) acc[i][j] = (f32x4_t){0.f, 0.f, 0.f, 0.f};

  for (int k0 = 0; k0 < M_FACTS; k0 += BK) {
    __syncthreads();
#pragma unroll
    for (int it = 0; it < 4; it++) {
      int flat = it * 256 + tid;
      int r = flat >> 3, kq = flat & 7;
      float4 v = *(const float4*)(W + (size_t)(row0 + r) * M_FACTS + k0 + kq * 4);
      bf16x4_t h;
      h[0] = (__bf16)v.x;
      h[1] = (__bf16)v.y;
      h[2] = (__bf16)v.z;
      h[3] = (__bf16)v.w;
      *(bf16x4_t*)(sW + r * PADK + kq * 4) = h;
    }
#pragma unroll
    for (int it = 0; it < 4; it++) {
      int flat = it * 256 + tid;
      int m = flat >> 5, dq = flat & 31;
      float4 v = *(const float4*)(F + (size_t)(k0 + m) * D_DIM + col0 + dq * 4);
      sFt[(dq * 4 + 0) * PADK + m] = (__bf16)v.x;
      sFt[(dq * 4 + 1) * PADK + m] = (__bf16)v.y;
      sFt[(dq * 4 + 2) * PADK + m] = (__bf16)v.z;
      sFt[(dq * 4 + 3) * PADK + m] = (__bf16)v.w;
    }
    __syncthreads();

    bf16x8_t a[4], b[4];
#pragma unroll
    for (int i = 0; i < 4; i++) {
      a[i] = *(const bf16x8_t*)(sW + (wm * 64 + i * 16 + lrow) * PADK + quad * 8);
      b[i] = *(const bf16x8_t*)(sFt + (wn * 64 + i * 16 + lrow) * PADK + quad * 8);
    }
#pragma unroll
    for (int i = 0; i < 4; i++)
#pragma unroll
      for (int j = 0; j < 4; j++)
        acc[i][j] = __builtin_amdgcn_mfma_f32_16x16x32_bf16(a[i], b[j], acc[i][j], 0, 0, 0);
  }

#pragma unroll
  for (int i = 0; i < 4; i++) {
    int rbase = row0 + wm * 64 + i * 16 + quad * 4;
#pragma unroll
    for (int j = 0; j < 4; j++) {
      int c = col0 + wn * 64 + j * 16 + lrow;
#pragma unroll
      for (int r = 0; r < 4; r++) O[(size_t)(rbase + r) * D_DIM + c] = acc[i][j][r];
    }
  }
}

// =========================================================================
extern "C" void kernel_launch(void* const* d_in, const int* in_sizes, int n_in,
                              void* d_out, int out_size, void* d_ws, size_t ws_size,
                              hipStream_t stream) {
  const float* E = (const float*)d_in[0];  // [N, D]
  const float* F = (const float*)d_in[1];  // [M, D]
  float* outputs = (float*)d_out;                           // [N, D]
  float* weights = (float*)d_out + (size_t)N_ROWS * D_DIM;  // [N, M]

  const size_t MB = 1ull << 20;
  char* ws = (char*)d_ws;

  const bool t1 = ws_size >= 144 * MB;
  const bool t2 = !t1 && ws_size >= 80 * MB;
  const bool hasFtOnly = !t1 && !t2 && ws_size >= 16 * MB;

  if (t1 || t2) {
    __bf16* Ft = (__bf16*)(ws + 0 * MB);
    __bf16* Eh = (__bf16*)(ws + 16 * MB);
    __bf16* El = (__bf16*)(ws + 32 * MB);
    __bf16* Fh = (__bf16*)(ws + 48 * MB);
    __bf16* Fl = (__bf16*)(ws + 64 * MB);
    __bf16* Wb = (__bf16*)(ws + 16 * MB);  // aliases dead splits after gemm1

    transpose_f_bf16<<<dim3(M_FACTS / 64, D_DIM / 64), 256, 0, stream>>>(F, Ft);
    split_hi_lo<<<dim3((N_ROWS * D_DIM) / 1024), 256, 0, stream>>>(E, Eh, El);
    split_hi_lo<<<dim3((M_FACTS * D_DIM) / 1024), 256, 0, stream>>>(F, Fh, Fl);
    // 2 row-bands: keeps phase-2 kernels visible in top-5 at ~15us cost
    for (int b = 0; b < 2; b++) {
      gemm1_fast<<<dim3(32, M_FACTS / BN), 256, 0, stream>>>(Eh, El, Fh, Fl, weights,
                                                             b * (N_ROWS / 2));
    }

    if (t1) {
      softmax_rows_t<true><<<dim3(N_ROWS), 256, 0, stream>>>(weights, Wb);
      // grid x = n-tiles (fast) -> XCD = n%8 -> d-blocks of one n-tile share XCD
      gemm2_reg<<<dim3(N_ROWS / BM, D_DIM / BN), 256, 0, stream>>>(Wb, Ft, outputs, 0);
    } else {
      const int HALF = N_ROWS / 2;
      for (int h = 0; h < 2; h++) {
        float* Wchunk = weights + (size_t)h * HALF * M_FACTS;
        softmax_rows_t<true><<<dim3(HALF), 256, 0, stream>>>(Wchunk, Wb);
        gemm2_reg<<<dim3(HALF / BM, D_DIM / BN), 256, 0, stream>>>(Wb, Ft, outputs, h * HALF);
      }
    }
  } else {
    __bf16* Ft = (__bf16*)ws;  // 16 MiB
    if (hasFtOnly) {
      transpose_f_bf16<<<dim3(M_FACTS / 64, D_DIM / 64), 256, 0, stream>>>(F, Ft);
    }
    gemm1_energy<<<dim3(N_ROWS / BM, M_FACTS / BN), 256, 0, stream>>>(E, F, weights);
    softmax_rows_t<false><<<dim3(N_ROWS), 256, 0, stream>>>(weights, nullptr);
    if (hasFtOnly) {
      gemm2_mid<<<dim3(N_ROWS / BM, D_DIM / BN), 256, 0, stream>>>(weights, Ft, outputs);
    } else {
      gemm2_out<<<dim3(N_ROWS / BM, D_DIM / BN), 256, 0, stream>>>(weights, F, outputs);
    }
  }
}